// Round 5
// baseline (178.935 us; speedup 1.0000x reference)
//
#include <hip/hip_runtime.h>
#include <math.h>

#define D 20
#define NT 256            // threads per block
#define RPB 512           // rows per block
#define RPT 2             // rows per thread (RPB / NT)

// ws word offsets (all float4-aligned):
//   [0..3]     acc[0]=sum_h, acc[1]=sum_abs (doubles)
//   [8..407]   M1tT[400]: [d][j] = sum_e W[e][d]*W_init[e][j]   (d-major)
//   [408..427] c[20]:     c[j] = sum_e b[e]*W_init[e][j] + 1
//   [428..827] Wt[400]:   [j][j2] = W[j2][j]                    (transposed)
#define WS_M1_OFF 8
#define WS_C_OFF 408
#define WS_WT_OFF 428

__global__ void prep_kernel(const float* __restrict__ W,
                            const float* __restrict__ b,
                            const float* __restrict__ Wi,
                            float* __restrict__ wsf) {
  int t = threadIdx.x;  // 1024 threads
  if (t < D * D) {
    int d = t / D, j = t % D;
    float a = 0.f;
#pragma unroll
    for (int e = 0; e < D; ++e) a = fmaf(W[e * D + d], Wi[e * D + j], a);
    wsf[WS_M1_OFF + t] = a;
  } else if (t < 2 * D * D) {
    int i = t - D * D;
    int j = i / D, j2 = i % D;
    wsf[WS_WT_OFF + i] = W[j2 * D + j];
  } else if (t < 2 * D * D + D) {
    int j = t - 2 * D * D;
    float a = 1.0f;
#pragma unroll
    for (int e = 0; e < D; ++e) a = fmaf(b[e], Wi[e * D + j], a);
    wsf[WS_C_OFF + j] = a;
  } else if (t == 2 * D * D + D) {
    double* acc = (double*)wsf;
    acc[0] = 0.0;
    acc[1] = 0.0;
  }
}

// Coalesced global->LDS staging; register-blocked compute from LDS.
// Rows per thread are block-strided (t, t+256): LDS read lane-stride is
// 20 words -> 20i mod 32 covers all eight 4-bank groups, 8 lanes each =
// LDS bandwidth floor (equivalent to dense), no padding needed.
__global__ __launch_bounds__(NT, 3) void fused_kernel(
    const float* __restrict__ X,
    const float* __restrict__ b,
    const float* __restrict__ wsf,
    double* __restrict__ acc,
    int nrows) {
  __shared__ __align__(16) float sX[RPB * D];  // 40960 B
  __shared__ __align__(16) float sM[D * D];    // M1tT, d-major
  __shared__ __align__(16) float sWt[D * D];   // W transposed, j-major
  __shared__ __align__(16) float sc[D];
  __shared__ __align__(16) float sb[D];
  __shared__ float sred[8];

  const int t = threadIdx.x;
  const int base = blockIdx.x * RPB;
  int slab = base;
  if (slab > nrows - RPB) slab = nrows - RPB;  // clamp (uniform per block)

  // --- Stage X slab into LDS, fully coalesced (10 float4/thread) ---
  const float4* __restrict__ G = (const float4*)(X + (long long)slab * D);
  float4* __restrict__ Sv = (float4*)sX;
  float4 vbuf[10];
#pragma unroll
  for (int s = 0; s < 10; ++s) vbuf[s] = G[s * NT + t];

  // --- Constants into LDS (cooperative, float4) ---
  if (t < 100) {
    ((float4*)sM)[t] = ((const float4*)(wsf + WS_M1_OFF))[t];
  } else if (t < 200) {
    ((float4*)sWt)[t - 100] = ((const float4*)(wsf + WS_WT_OFF))[t - 100];
  } else if (t < 205) {
    ((float4*)sc)[t - 200] = ((const float4*)(wsf + WS_C_OFF))[t - 200];
  } else if (t < 210) {
    ((float4*)sb)[t - 205] = ((const float4*)b)[t - 205];
  }

#pragma unroll
  for (int s = 0; s < 10; ++s) Sv[s * NT + t] = vbuf[s];
  __syncthreads();

  // --- Read this thread's 2 rows from LDS into registers ---
  float xa[RPT][D];
#pragma unroll
  for (int k = 0; k < RPT; ++k) {
    const float4* rv = (const float4*)&sX[(t + k * NT) * D];
#pragma unroll
    for (int jv = 0; jv < 5; ++jv) {
      float4 v = rv[jv];
      xa[k][4 * jv + 0] = v.x;
      xa[k][4 * jv + 1] = v.y;
      xa[k][4 * jv + 2] = v.z;
      xa[k][4 * jv + 3] = v.w;
    }
  }

  // --- Stage 1: h2 = x @ M1 + c, d-major rank-1 (20 indep accs/row) ---
  float h2[RPT][D];
  {
    const float4* cv = (const float4*)sc;
#pragma unroll
    for (int jv = 0; jv < 5; ++jv) {
      float4 cc = cv[jv];
#pragma unroll
      for (int k = 0; k < RPT; ++k) {
        h2[k][4 * jv + 0] = cc.x;
        h2[k][4 * jv + 1] = cc.y;
        h2[k][4 * jv + 2] = cc.z;
        h2[k][4 * jv + 3] = cc.w;
      }
    }
  }
#pragma unroll
  for (int d = 0; d < D; ++d) {
    const float4* mr = (const float4*)&sM[d * D];  // wave-uniform broadcast
    const float x0 = xa[0][d], x1 = xa[1][d];
#pragma unroll
    for (int jv = 0; jv < 5; ++jv) {
      float4 m = mr[jv];
      h2[0][4 * jv + 0] = fmaf(x0, m.x, h2[0][4 * jv + 0]);
      h2[1][4 * jv + 0] = fmaf(x1, m.x, h2[1][4 * jv + 0]);
      h2[0][4 * jv + 1] = fmaf(x0, m.y, h2[0][4 * jv + 1]);
      h2[1][4 * jv + 1] = fmaf(x1, m.y, h2[1][4 * jv + 1]);
      h2[0][4 * jv + 2] = fmaf(x0, m.z, h2[0][4 * jv + 2]);
      h2[1][4 * jv + 2] = fmaf(x1, m.z, h2[1][4 * jv + 2]);
      h2[0][4 * jv + 3] = fmaf(x0, m.w, h2[0][4 * jv + 3]);
      h2[1][4 * jv + 3] = fmaf(x1, m.w, h2[1][4 * jv + 3]);
    }
  }

  // --- Stage 2: h3 = relu(h2) @ W^T + b, j-major rank-1 via W transposed ---
  float h3[RPT][D];
  {
    const float4* bv = (const float4*)sb;
#pragma unroll
    for (int jv = 0; jv < 5; ++jv) {
      float4 bb = bv[jv];
#pragma unroll
      for (int k = 0; k < RPT; ++k) {
        h3[k][4 * jv + 0] = bb.x;
        h3[k][4 * jv + 1] = bb.y;
        h3[k][4 * jv + 2] = bb.z;
        h3[k][4 * jv + 3] = bb.w;
      }
    }
  }
#pragma unroll
  for (int j = 0; j < D; ++j) {
    const float4* wr = (const float4*)&sWt[j * D];  // wave-uniform broadcast
    const float p0 = fmaxf(h2[0][j], 0.f);
    const float p1 = fmaxf(h2[1][j], 0.f);
#pragma unroll
    for (int jv = 0; jv < 5; ++jv) {
      float4 w = wr[jv];
      h3[0][4 * jv + 0] = fmaf(p0, w.x, h3[0][4 * jv + 0]);
      h3[1][4 * jv + 0] = fmaf(p1, w.x, h3[1][4 * jv + 0]);
      h3[0][4 * jv + 1] = fmaf(p0, w.y, h3[0][4 * jv + 1]);
      h3[1][4 * jv + 1] = fmaf(p1, w.y, h3[1][4 * jv + 1]);
      h3[0][4 * jv + 2] = fmaf(p0, w.z, h3[0][4 * jv + 2]);
      h3[1][4 * jv + 2] = fmaf(p1, w.z, h3[1][4 * jv + 2]);
      h3[0][4 * jv + 3] = fmaf(p0, w.w, h3[0][4 * jv + 3]);
      h3[1][4 * jv + 3] = fmaf(p1, w.w, h3[1][4 * jv + 3]);
    }
  }

  // --- Masked per-row sums (branchless tail) ---
  float rs = 0.f, ra = 0.f;
#pragma unroll
  for (int k = 0; k < RPT; ++k) {
    float s = 0.f, a = 0.f;
#pragma unroll
    for (int j = 0; j < D; ++j) {
      s += h3[k][j];
      a += fabsf(h3[k][j]);
    }
    const float valid = (slab + t + k * NT >= base) ? 1.0f : 0.0f;
    rs = fmaf(valid, s, rs);
    ra = fmaf(valid, a, ra);
  }

  // --- Wave shuffle reduce -> cross-wave LDS -> one fp64 atomic/block ---
#pragma unroll
  for (int off = 32; off > 0; off >>= 1) {
    rs += __shfl_down(rs, off, 64);
    ra += __shfl_down(ra, off, 64);
  }
  const int wave = t >> 6, lane = t & 63;
  if (lane == 0) {
    sred[wave] = rs;
    sred[4 + wave] = ra;
  }
  __syncthreads();
  if (t == 0) {
    float s1 = sred[0] + sred[1] + sred[2] + sred[3];
    float s2 = sred[4] + sred[5] + sred[6] + sred[7];
    atomicAdd(&acc[0], (double)s1);
    atomicAdd(&acc[1], (double)s2);
  }
}

// Single-thread finalize: count halvings of sum(|h|), scale sum(h) by 2^-k.
__global__ void fin_kernel(const double* __restrict__ acc, float* __restrict__ out) {
  double s = acc[1];
  int k = 0;
  while (s > 1.0 && k < 1100) {
    s *= 0.5;
    ++k;
  }
  out[0] = ldexpf((float)acc[0], -k);
}

extern "C" void kernel_launch(void* const* d_in, const int* in_sizes, int n_in,
                              void* d_out, int out_size, void* d_ws, size_t ws_size,
                              hipStream_t stream) {
  const float* X = (const float*)d_in[0];
  const float* W = (const float*)d_in[1];
  const float* b = (const float*)d_in[2];
  const float* Wi = (const float*)d_in[3];
  float* out = (float*)d_out;
  float* wsf = (float*)d_ws;
  double* acc = (double*)d_ws;

  const int nrows = in_sizes[0] / D;  // 1,000,000

  hipLaunchKernelGGL(prep_kernel, dim3(1), dim3(1024), 0, stream, W, b, Wi, wsf);

  const int nblocks = (nrows + RPB - 1) / RPB;
  hipLaunchKernelGGL(fused_kernel, dim3(nblocks), dim3(NT), 0, stream,
                     X, b, wsf, acc, nrows);

  hipLaunchKernelGGL(fin_kernel, dim3(1), dim3(1), 0, stream, acc, out);
}